// Round 1
// baseline (227.997 us; speedup 1.0000x reference)
//
#include <hip/hip_runtime.h>
#include <math.h>

#define D 128
#define K 1024
#define BM 64
#define BK 64          // codes per chunk
#define NCHUNK (K / BK)
#define APAD 132       // 128 + 4 pad: float4-aligned, spreads banks

// ws layout:
// [0, 4096)      : hist (1024 x int)
// [4096, 4100)   : loss accumulator (float)
// [8192, 12288)  : cnorm (1024 x float)

__global__ void cnorm_kernel(const float* __restrict__ codebook, float* __restrict__ cnorm) {
    int c = blockIdx.x * blockDim.x + threadIdx.x;
    if (c >= K) return;
    const float4* row = reinterpret_cast<const float4*>(codebook + (size_t)c * D);
    float s = 0.f;
#pragma unroll
    for (int i = 0; i < D / 4; ++i) {
        float4 v = row[i];
        s += v.x * v.x + v.y * v.y + v.z * v.z + v.w * v.w;
    }
    cnorm[c] = s;
}

__global__ __launch_bounds__(256, 2)
void vq_main(const float* __restrict__ z, const float* __restrict__ codebook,
             const float* __restrict__ cnorm, int* __restrict__ hist,
             float* __restrict__ loss_accum,
             float* __restrict__ out_zq, float* __restrict__ out_idx,
             float* __restrict__ out_dist) {
    __shared__ float As[BM][APAD];
    __shared__ float Bs[BM][APAD];
    __shared__ float xnorm_s[BM];
    __shared__ int   best_s[BM];

    const int t = threadIdx.x;
    const int row_base = blockIdx.x * BM;
    const int tr = t >> 4;   // 0..15 row group (4 rows each)
    const int tc = t & 15;   // 0..15 code group (4 codes each)

    // ---- stage A tile: 64 rows x 128 floats ----
    {
        const float4* zg = reinterpret_cast<const float4*>(z + (size_t)row_base * D);
#pragma unroll
        for (int k = 0; k < 8; ++k) {
            int f = t + k * 256;      // 0..2047
            int r = f >> 5;
            int d4 = f & 31;
            float4 v = zg[r * 32 + d4];
            *reinterpret_cast<float4*>(&As[r][d4 * 4]) = v;
        }
    }
    __syncthreads();
    if (t < BM) {
        float s = 0.f;
#pragma unroll
        for (int d4 = 0; d4 < 32; ++d4) {
            float4 v = *reinterpret_cast<const float4*>(&As[t][d4 * 4]);
            s += v.x * v.x + v.y * v.y + v.z * v.z + v.w * v.w;
        }
        xnorm_s[t] = s;
    }

    // per-thread top-2 tracking for 4 rows
    float v1[4], v2[4];
    int   i1[4], i2[4];
#pragma unroll
    for (int i = 0; i < 4; ++i) { v1[i] = INFINITY; v2[i] = INFINITY; i1[i] = K; i2[i] = K; }

    for (int chunk = 0; chunk < NCHUNK; ++chunk) {
        __syncthreads();   // protect Bs overwrite vs previous chunk compute
        {
            const float4* cg = reinterpret_cast<const float4*>(codebook + (size_t)chunk * BK * D);
#pragma unroll
            for (int k = 0; k < 8; ++k) {
                int f = t + k * 256;
                int r = f >> 5;
                int d4 = f & 31;
                float4 v = cg[r * 32 + d4];
                *reinterpret_cast<float4*>(&Bs[r][d4 * 4]) = v;
            }
        }
        __syncthreads();

        float acc[4][4];
#pragma unroll
        for (int i = 0; i < 4; ++i)
#pragma unroll
            for (int j = 0; j < 4; ++j) acc[i][j] = 0.f;

#pragma unroll 4
        for (int d4 = 0; d4 < 32; ++d4) {
            float4 a[4], b[4];
#pragma unroll
            for (int i = 0; i < 4; ++i)
                a[i] = *reinterpret_cast<const float4*>(&As[tr * 4 + i][d4 * 4]);
#pragma unroll
            for (int j = 0; j < 4; ++j)
                b[j] = *reinterpret_cast<const float4*>(&Bs[tc * 4 + j][d4 * 4]);
#pragma unroll
            for (int i = 0; i < 4; ++i)
#pragma unroll
                for (int j = 0; j < 4; ++j) {
                    acc[i][j] += a[i].x * b[j].x;
                    acc[i][j] += a[i].y * b[j].y;
                    acc[i][j] += a[i].z * b[j].z;
                    acc[i][j] += a[i].w * b[j].w;
                }
        }

        // epilogue: distances + top-2 update (codes ascending => first-min tiebreak kept)
        float cn[4];
#pragma unroll
        for (int j = 0; j < 4; ++j) cn[j] = cnorm[chunk * BK + tc * 4 + j];
#pragma unroll
        for (int i = 0; i < 4; ++i) {
            int r = tr * 4 + i;
            float xn = xnorm_s[r];
            float dvals[4];
#pragma unroll
            for (int j = 0; j < 4; ++j) {
                int code = chunk * BK + tc * 4 + j;
                float dist = xn - 2.f * acc[i][j] + cn[j];
                dvals[j] = dist;
                if (dist < v1[i]) { v2[i] = v1[i]; i2[i] = i1[i]; v1[i] = dist; i1[i] = code; }
                else if (dist < v2[i]) { v2[i] = dist; i2[i] = code; }
            }
            float4 dv = make_float4(dvals[0], dvals[1], dvals[2], dvals[3]);
            size_t off = (size_t)(row_base + r) * K + (size_t)chunk * BK + tc * 4;
            *reinterpret_cast<float4*>(out_dist + off) = dv;
        }
    }

    __syncthreads();
    // cross-thread top-2 reduction; reuse Bs as scratch (16 KB needed, 33 KB available)
    float* rv1 = &Bs[0][0];
    float* rv2 = rv1 + 64 * 16;
    int*   ri1 = reinterpret_cast<int*>(rv2 + 64 * 16);
    int*   ri2 = ri1 + 64 * 16;
#pragma unroll
    for (int i = 0; i < 4; ++i) {
        int r = tr * 4 + i;
        rv1[r * 16 + tc] = v1[i];
        rv2[r * 16 + tc] = v2[i];
        ri1[r * 16 + tc] = i1[i];
        ri2[r * 16 + tc] = i2[i];
    }
    __syncthreads();

    if (t < BM) {
        float bv = INFINITY, sv = INFINITY;
        int bi = K, si = K;
        for (int s = 0; s < 16; ++s) {
            float cv1 = rv1[t * 16 + s]; int ci1 = ri1[t * 16 + s];
            float cv2 = rv2[t * 16 + s]; int ci2 = ri2[t * 16 + s];
            if (cv1 < bv || (cv1 == bv && ci1 < bi)) { sv = bv; si = bi; bv = cv1; bi = ci1; }
            else if (cv1 < sv || (cv1 == sv && ci1 < si)) { sv = cv1; si = ci1; }
            if (cv2 < bv || (cv2 == bv && ci2 < bi)) { sv = bv; si = bi; bv = cv2; bi = ci2; }
            else if (cv2 < sv || (cv2 == sv && ci2 < si)) { sv = cv2; si = ci2; }
        }
        // fp64 refinement between top-2: decides near-ties at float64 accuracy
        int final_idx = bi;
        if (si < K) {
            const float* c1 = codebook + (size_t)bi * D;
            const float* c2 = codebook + (size_t)si * D;
            double d1 = 0.0, d2 = 0.0;
            for (int d = 0; d < D; ++d) {
                double x = (double)As[t][d];
                double e1 = x - (double)c1[d];
                double e2 = x - (double)c2[d];
                d1 += e1 * e1;
                d2 += e2 * e2;
            }
            if (d2 < d1 || (d2 == d1 && si < bi)) final_idx = si;
        }
        best_s[t] = final_idx;
        out_idx[row_base + t] = (float)final_idx;
        atomicAdd(&hist[final_idx], 1);
    }
    __syncthreads();

    // z_q gather + loss partial (coalesced: consecutive e => consecutive d)
    float partial = 0.f;
#pragma unroll
    for (int k = 0; k < 32; ++k) {
        int e = t + k * 256;       // 0..8191
        int r = e >> 7;
        int d = e & 127;
        int idx = best_s[r];
        float q = codebook[(size_t)idx * D + d];
        float zz = As[r][d];
        float diff = q - zz;
        partial += diff * diff;
        out_zq[(size_t)(row_base + r) * D + d] = q;
    }
    for (int off = 32; off > 0; off >>= 1)
        partial += __shfl_down(partial, off);
    if ((t & 63) == 0) atomicAdd(loss_accum, partial);
}

__global__ void vq_finalize(const int* __restrict__ hist, const float* __restrict__ loss_accum,
                            float* __restrict__ out_scalars, int M) {
    __shared__ float red[256];
    int t = threadIdx.x;
    float s = 0.f;
    float invM = 1.0f / (float)M;
#pragma unroll
    for (int k = 0; k < K / 256; ++k) {
        float p = (float)hist[t + k * 256] * invM;
        s += p * logf(p + 1e-10f);
    }
    red[t] = s;
    __syncthreads();
    for (int off = 128; off > 0; off >>= 1) {
        if (t < off) red[t] += red[t + off];
        __syncthreads();
    }
    if (t == 0) {
        float loss = loss_accum[0] / ((float)M * (float)D);
        out_scalars[0] = 0.25f * loss;    // commit_loss
        out_scalars[1] = loss;            // codebook_loss
        out_scalars[2] = expf(-red[0]);   // perplexity
    }
}

extern "C" void kernel_launch(void* const* d_in, const int* in_sizes, int n_in,
                              void* d_out, int out_size, void* d_ws, size_t ws_size,
                              hipStream_t stream) {
    const float* z = (const float*)d_in[0];
    const float* codebook = (const float*)d_in[1];
    int M = in_sizes[0] / D;   // 32768

    float* out = (float*)d_out;
    float* out_zq = out;                                  // M*D
    float* out_idx = out + (size_t)M * D;                 // M
    float* out_scalars = out_idx + M;                     // 3: commit, codebook, perplexity
    float* out_dist = out_scalars + 3;                    // M*K

    int*   hist = (int*)d_ws;
    float* loss_accum = (float*)((char*)d_ws + 4096);
    float* cnorm = (float*)((char*)d_ws + 8192);

    hipMemsetAsync(d_ws, 0, 8192, stream);
    cnorm_kernel<<<K / 256, 256, 0, stream>>>(codebook, cnorm);
    vq_main<<<M / BM, 256, 0, stream>>>(z, codebook, cnorm, hist, loss_accum,
                                        out_zq, out_idx, out_dist);
    vq_finalize<<<1, 256, 0, stream>>>(hist, loss_accum, out_scalars, M);
}

// Round 2
// 113.844 us; speedup vs baseline: 2.0027x; 2.0027x over previous
//
#include <hip/hip_runtime.h>
#include <math.h>

#define D 128
#define K 1024
#define BM 64
#define BN 64
#define NCHUNK (K / BN)
#define PAD 136   // bf16 elements per LDS row: 272B stride, 16B-aligned, spreads banks

typedef __attribute__((ext_vector_type(8))) short bf16x8;
typedef __attribute__((ext_vector_type(4))) float f32x4;
typedef unsigned short u16;

// ws layout: [0,4096) hist (1024 int) | [4096,4100) loss accum | [8192,12288) cnorm

__device__ __forceinline__ u16 f2bf(float x) {
    union { float f; unsigned u; } v; v.f = x;
    unsigned r = (v.u + 0x7FFFu + ((v.u >> 16) & 1u)) >> 16;
    return (u16)r;
}
__device__ __forceinline__ float bf2f(u16 b) {
    union { float f; unsigned u; } v; v.u = ((unsigned)b) << 16;
    return v.f;
}

__global__ void cnorm_kernel(const float* __restrict__ codebook, float* __restrict__ cnorm) {
    int c = blockIdx.x * blockDim.x + threadIdx.x;
    if (c >= K) return;
    const float4* row = reinterpret_cast<const float4*>(codebook + (size_t)c * D);
    float s = 0.f;
#pragma unroll
    for (int i = 0; i < D / 4; ++i) {
        float4 v = row[i];
        s += v.x * v.x + v.y * v.y + v.z * v.z + v.w * v.w;
    }
    cnorm[c] = s;
}

__global__ __launch_bounds__(256, 2)
void vq_main(const float* __restrict__ z, const float* __restrict__ codebook,
             const float* __restrict__ cnorm, int* __restrict__ hist,
             float* __restrict__ loss_accum,
             float* __restrict__ out_zq, float* __restrict__ out_idx,
             float* __restrict__ out_dist) {
    __shared__ u16 Ah[BM][PAD], Al[BM][PAD];
    __shared__ u16 Bh[BN][PAD], Bl[BN][PAD];
    __shared__ float xn_s[BM];
    __shared__ float cn_s[K];
    __shared__ int bi_s[BM], si_s[BM], best_s[BM];

    const int t = threadIdx.x;
    const int lane = t & 63;
    const int wave = t >> 6;
    const int lr = lane & 15;   // fragment row (A) / col (B) within 16
    const int lg = lane >> 4;   // k-group (8 bf16 each)
    const int row_base = blockIdx.x * BM;

    if (t < BM) xn_s[t] = 0.f;
    __syncthreads();

    // ---- stage A tile (fp32 -> hi/lo bf16) + xnorm partials ----
    {
        const float4* zg = reinterpret_cast<const float4*>(z + (size_t)row_base * D);
#pragma unroll
        for (int k = 0; k < 8; ++k) {
            int f = t + k * 256;        // 0..2047 over 64 rows x 32 float4
            int r = f >> 5, d4 = f & 31;
            float4 v = zg[f];
            u16 h0 = f2bf(v.x), h1 = f2bf(v.y), h2 = f2bf(v.z), h3 = f2bf(v.w);
            u16 l0 = f2bf(v.x - bf2f(h0)), l1 = f2bf(v.y - bf2f(h1));
            u16 l2 = f2bf(v.z - bf2f(h2)), l3 = f2bf(v.w - bf2f(h3));
            *reinterpret_cast<ushort4*>(&Ah[r][d4 * 4]) = make_ushort4(h0, h1, h2, h3);
            *reinterpret_cast<ushort4*>(&Al[r][d4 * 4]) = make_ushort4(l0, l1, l2, l3);
            atomicAdd(&xn_s[r], v.x * v.x + v.y * v.y + v.z * v.z + v.w * v.w);
        }
#pragma unroll
        for (int k = 0; k < 4; ++k) cn_s[t + k * 256] = cnorm[t + k * 256];
    }
    __syncthreads();

    // ---- hoist A fragments (rows = wave*16 + lr) and xnorm into registers ----
    const int arow = wave * 16 + lr;
    bf16x8 afh[4], afl[4];
#pragma unroll
    for (int kb = 0; kb < 4; ++kb) {
        afh[kb] = *reinterpret_cast<const bf16x8*>(&Ah[arow][kb * 32 + lg * 8]);
        afl[kb] = *reinterpret_cast<const bf16x8*>(&Al[arow][kb * 32 + lg * 8]);
    }
    float xn[4];
#pragma unroll
    for (int q = 0; q < 4; ++q) xn[q] = xn_s[wave * 16 + lg * 4 + q];

    float v1[4], v2[4];
    int i1[4], i2[4];
#pragma unroll
    for (int q = 0; q < 4; ++q) { v1[q] = INFINITY; v2[q] = INFINITY; i1[q] = K; i2[q] = K; }

    for (int c = 0; c < NCHUNK; ++c) {
        __syncthreads();   // guard B overwrite vs previous chunk's reads
        {
            const float4* cg = reinterpret_cast<const float4*>(codebook + (size_t)c * BN * D);
#pragma unroll
            for (int k = 0; k < 8; ++k) {
                int f = t + k * 256;
                int r = f >> 5, d4 = f & 31;
                float4 v = cg[f];
                u16 h0 = f2bf(v.x), h1 = f2bf(v.y), h2 = f2bf(v.z), h3 = f2bf(v.w);
                u16 l0 = f2bf(v.x - bf2f(h0)), l1 = f2bf(v.y - bf2f(h1));
                u16 l2 = f2bf(v.z - bf2f(h2)), l3 = f2bf(v.w - bf2f(h3));
                *reinterpret_cast<ushort4*>(&Bh[r][d4 * 4]) = make_ushort4(h0, h1, h2, h3);
                *reinterpret_cast<ushort4*>(&Bl[r][d4 * 4]) = make_ushort4(l0, l1, l2, l3);
            }
        }
        __syncthreads();

        f32x4 acc[4];
#pragma unroll
        for (int nt = 0; nt < 4; ++nt) { acc[nt][0] = 0.f; acc[nt][1] = 0.f; acc[nt][2] = 0.f; acc[nt][3] = 0.f; }

#pragma unroll
        for (int kb = 0; kb < 4; ++kb) {
            bf16x8 bh[4], bl[4];
#pragma unroll
            for (int nt = 0; nt < 4; ++nt) {
                bh[nt] = *reinterpret_cast<const bf16x8*>(&Bh[nt * 16 + lr][kb * 32 + lg * 8]);
                bl[nt] = *reinterpret_cast<const bf16x8*>(&Bl[nt * 16 + lr][kb * 32 + lg * 8]);
            }
#pragma unroll
            for (int nt = 0; nt < 4; ++nt) {
                acc[nt] = __builtin_amdgcn_mfma_f32_16x16x32_bf16(afh[kb], bh[nt], acc[nt], 0, 0, 0);
                acc[nt] = __builtin_amdgcn_mfma_f32_16x16x32_bf16(afh[kb], bl[nt], acc[nt], 0, 0, 0);
                acc[nt] = __builtin_amdgcn_mfma_f32_16x16x32_bf16(afl[kb], bh[nt], acc[nt], 0, 0, 0);
            }
        }

        // epilogue: distances + writes + top-2 (cols ascending per lane => first-min kept)
#pragma unroll
        for (int nt = 0; nt < 4; ++nt) {
            int col = c * BN + nt * 16 + lr;
            float cn = cn_s[col];
            float* orow = out_dist + (size_t)(row_base + wave * 16 + lg * 4) * K + col;
#pragma unroll
            for (int q = 0; q < 4; ++q) {
                float dist = xn[q] - 2.f * acc[nt][q] + cn;
                orow[(size_t)q * K] = dist;
                if (dist < v1[q]) { v2[q] = v1[q]; i2[q] = i1[q]; v1[q] = dist; i1[q] = col; }
                else if (dist < v2[q]) { v2[q] = dist; i2[q] = col; }
            }
        }
    }

    __syncthreads();
    // ---- cross-lane top-2 reduction via LDS scratch (reuse B buffers) ----
    float* rv1 = reinterpret_cast<float*>(&Bh[0][0]);
    float* rv2 = rv1 + BM * 16;
    int* ri1 = reinterpret_cast<int*>(&Bl[0][0]);
    int* ri2 = ri1 + BM * 16;
#pragma unroll
    for (int q = 0; q < 4; ++q) {
        int rl = wave * 16 + lg * 4 + q;
        rv1[rl * 16 + lr] = v1[q];
        rv2[rl * 16 + lr] = v2[q];
        ri1[rl * 16 + lr] = i1[q];
        ri2[rl * 16 + lr] = i2[q];
    }
    __syncthreads();

    if (t < BM) {
        float bv = INFINITY, sv = INFINITY;
        int bi = K, si = K;
        for (int s = 0; s < 16; ++s) {
            float cv1 = rv1[t * 16 + s]; int ci1 = ri1[t * 16 + s];
            float cv2 = rv2[t * 16 + s]; int ci2 = ri2[t * 16 + s];
            if (cv1 < bv || (cv1 == bv && ci1 < bi)) { sv = bv; si = bi; bv = cv1; bi = ci1; }
            else if (cv1 < sv || (cv1 == sv && ci1 < si)) { sv = cv1; si = ci1; }
            if (cv2 < bv || (cv2 == bv && ci2 < bi)) { sv = bv; si = bi; bv = cv2; bi = ci2; }
            else if (cv2 < sv || (cv2 == sv && ci2 < si)) { sv = cv2; si = ci2; }
        }
        bi_s[t] = bi;
        si_s[t] = si;
    }
    __syncthreads();

    // ---- fp64 refinement (4 threads/row): exact top-2 decision + loss (= ||q-z||^2) ----
    {
        const int rr = t >> 2, t4 = t & 3;
        const int bi = bi_s[rr], si = si_s[rr];
        const float4* zr = reinterpret_cast<const float4*>(z + (size_t)(row_base + rr) * D);
        const float4* c1 = reinterpret_cast<const float4*>(codebook + (size_t)bi * D);
        const float4* c2 = reinterpret_cast<const float4*>(codebook + (size_t)si * D);
        double d1 = 0.0, d2 = 0.0;
#pragma unroll
        for (int j = 0; j < 8; ++j) {
            float4 xv = zr[t4 * 8 + j];
            float4 a = c1[t4 * 8 + j];
            float4 b = c2[t4 * 8 + j];
            double e;
            e = (double)xv.x - (double)a.x; d1 += e * e;
            e = (double)xv.y - (double)a.y; d1 += e * e;
            e = (double)xv.z - (double)a.z; d1 += e * e;
            e = (double)xv.w - (double)a.w; d1 += e * e;
            e = (double)xv.x - (double)b.x; d2 += e * e;
            e = (double)xv.y - (double)b.y; d2 += e * e;
            e = (double)xv.z - (double)b.z; d2 += e * e;
            e = (double)xv.w - (double)b.w; d2 += e * e;
        }
        d1 += __shfl_xor(d1, 1); d1 += __shfl_xor(d1, 2);
        d2 += __shfl_xor(d2, 1); d2 += __shfl_xor(d2, 2);
        float lossv = 0.f;
        if (t4 == 0) {
            int fi = bi; double dmin = d1;
            if (d2 < d1 || (d2 == d1 && si < bi)) { fi = si; dmin = d2; }
            best_s[rr] = fi;
            out_idx[row_base + rr] = (float)fi;
            atomicAdd(&hist[fi], 1);
            lossv = (float)dmin;
        }
#pragma unroll
        for (int o = 32; o > 0; o >>= 1) lossv += __shfl_down(lossv, o);
        if (lane == 0) atomicAdd(loss_accum, lossv);
    }
    __syncthreads();

    // ---- z_q gather (vectorized, coalesced) ----
    {
        const float4* cb4 = reinterpret_cast<const float4*>(codebook);
        float4* zq4 = reinterpret_cast<float4*>(out_zq + (size_t)row_base * D);
#pragma unroll
        for (int k = 0; k < 8; ++k) {
            int f = t + k * 256;
            int r = f >> 5, d4 = f & 31;
            zq4[f] = cb4[(size_t)best_s[r] * 32 + d4];
        }
    }
}

__global__ void vq_finalize(const int* __restrict__ hist, const float* __restrict__ loss_accum,
                            float* __restrict__ out_scalars, int M) {
    __shared__ float red[256];
    int t = threadIdx.x;
    float s = 0.f;
    float invM = 1.0f / (float)M;
#pragma unroll
    for (int k = 0; k < K / 256; ++k) {
        float p = (float)hist[t + k * 256] * invM;
        s += p * logf(p + 1e-10f);
    }
    red[t] = s;
    __syncthreads();
    for (int off = 128; off > 0; off >>= 1) {
        if (t < off) red[t] += red[t + off];
        __syncthreads();
    }
    if (t == 0) {
        float loss = loss_accum[0] / ((float)M * (float)D);
        out_scalars[0] = 0.25f * loss;    // commit_loss
        out_scalars[1] = loss;            // codebook_loss
        out_scalars[2] = expf(-red[0]);   // perplexity
    }
}

extern "C" void kernel_launch(void* const* d_in, const int* in_sizes, int n_in,
                              void* d_out, int out_size, void* d_ws, size_t ws_size,
                              hipStream_t stream) {
    const float* z = (const float*)d_in[0];
    const float* codebook = (const float*)d_in[1];
    int M = in_sizes[0] / D;   // 32768

    float* out = (float*)d_out;
    float* out_zq = out;                                  // M*D
    float* out_idx = out + (size_t)M * D;                 // M
    float* out_scalars = out_idx + M;                     // 3
    float* out_dist = out_scalars + 3;                    // M*K

    int*   hist = (int*)d_ws;
    float* loss_accum = (float*)((char*)d_ws + 4096);
    float* cnorm = (float*)((char*)d_ws + 8192);

    hipMemsetAsync(d_ws, 0, 8192, stream);
    cnorm_kernel<<<K / 256, 256, 0, stream>>>(codebook, cnorm);
    vq_main<<<M / BM, 256, 0, stream>>>(z, codebook, cnorm, hist, loss_accum,
                                        out_zq, out_idx, out_dist);
    vq_finalize<<<1, 256, 0, stream>>>(hist, loss_accum, out_scalars, M);
}